// Round 4
// baseline (11792.133 us; speedup 1.0000x reference)
//
#include <hip/hip_runtime.h>
#include <cmath>

// Problem constants
#define Bb   64
#define Tt   128
#define Dd   2048
#define Hh   512
#define Gg   2048      // 4*H
#define Cc   101
#define ROWS 8192      // B*T

// ---------------- SGEMM (fp32, vector ALU) ----------------
#define BM 128
#define BN 128
#define BK 16

__global__ __launch_bounds__(256)
void sgemm_bias(const float* __restrict__ A, const float* __restrict__ B,
                const float* __restrict__ bias, float* __restrict__ C,
                int M, int N, int K) {
  __shared__ float As[BK][BM];
  __shared__ float Bs[BK][BN];
  const int tid  = threadIdx.x;
  const int bn   = blockIdx.x;
  const int bm   = blockIdx.y;
  const int row0 = bm * BM, col0 = bn * BN;
  const int tr = (tid >> 4) << 3;
  const int tc = (tid & 15) << 3;

  float acc[8][8];
#pragma unroll
  for (int i = 0; i < 8; ++i)
#pragma unroll
    for (int j = 0; j < 8; ++j) acc[i][j] = 0.f;

  const int arow = tid >> 1;
  const int acol = (tid & 1) << 3;
  const int brow = tid >> 4;
  const int bcol = (tid & 15) << 3;
  const float* Ap = A + (size_t)(row0 + arow) * K + acol;
  const float* Bp = B + (size_t)brow * N + (col0 + bcol);

  for (int k0 = 0; k0 < K; k0 += BK) {
    const float4 a0 = *(const float4*)(Ap + k0);
    const float4 a1 = *(const float4*)(Ap + k0 + 4);
    const float4 bv0 = *(const float4*)(Bp + (size_t)k0 * N);
    const float4 bv1 = *(const float4*)(Bp + (size_t)k0 * N + 4);
    As[acol + 0][arow] = a0.x;
    As[acol + 1][arow] = a0.y;
    As[acol + 2][arow] = a0.z;
    As[acol + 3][arow] = a0.w;
    As[acol + 4][arow] = a1.x;
    As[acol + 5][arow] = a1.y;
    As[acol + 6][arow] = a1.z;
    As[acol + 7][arow] = a1.w;
    *(float4*)(&Bs[brow][bcol])     = bv0;
    *(float4*)(&Bs[brow][bcol + 4]) = bv1;
    __syncthreads();
#pragma unroll
    for (int k = 0; k < BK; ++k) {
      float a[8], b[8];
      *(float4*)(a)     = *(const float4*)(&As[k][tr]);
      *(float4*)(a + 4) = *(const float4*)(&As[k][tr + 4]);
      *(float4*)(b)     = *(const float4*)(&Bs[k][tc]);
      *(float4*)(b + 4) = *(const float4*)(&Bs[k][tc + 4]);
#pragma unroll
      for (int i = 0; i < 8; ++i)
#pragma unroll
        for (int j = 0; j < 8; ++j)
          acc[i][j] = fmaf(a[i], b[j], acc[i][j]);
    }
    __syncthreads();
  }

  float bj[8];
#pragma unroll
  for (int j = 0; j < 8; ++j) bj[j] = bias[col0 + tc + j];
#pragma unroll
  for (int i = 0; i < 8; ++i) {
    float* Cp = C + (size_t)(row0 + tr + i) * N + (col0 + tc);
    float4 o0, o1;
    o0.x = acc[i][0] + bj[0]; o0.y = acc[i][1] + bj[1];
    o0.z = acc[i][2] + bj[2]; o0.w = acc[i][3] + bj[3];
    o1.x = acc[i][4] + bj[4]; o1.y = acc[i][5] + bj[5];
    o1.z = acc[i][6] + bj[6]; o1.w = acc[i][7] + bj[7];
    *(float4*)(Cp)     = o0;
    *(float4*)(Cp + 4) = o1;
  }
}

// ---------------- weight transpose ----------------
// WT[mat][c][k], mat0 = W1h (W1 rows D..D+511), mat1 = W2 top, mat2 = W2 bottom.
__global__ __launch_bounds__(256)
void transposeW(const float* __restrict__ W1, const float* __restrict__ W2,
                float* __restrict__ WT) {
  __shared__ float tl[32][33];
  const int tx = threadIdx.x, ty = threadIdx.y;   // 32, 8
  const int k0 = blockIdx.x * 32, c0 = blockIdx.y * 32, mat = blockIdx.z;
  const float* src;
  if (mat == 0)      src = W1 + (size_t)Dd * Gg;
  else if (mat == 1) src = W2;
  else               src = W2 + (size_t)Hh * Gg;
#pragma unroll
  for (int j = 0; j < 4; ++j)
    tl[ty + j * 8][tx] = src[(size_t)(k0 + ty + j * 8) * Gg + (c0 + tx)];
  __syncthreads();
  float* dst = WT + (size_t)mat * Gg * Hh;
#pragma unroll
  for (int j = 0; j < 4; ++j)
    dst[(size_t)(c0 + ty + j * 8) * Hh + (k0 + tx)] = tl[tx][ty + j * 8];
}

__global__ void init_bar(unsigned* bar) { if (threadIdx.x == 0) *bar = 0; }

__device__ __forceinline__ float dot4(float acc, float4 hv, float4 wv) {
  return fmaf(hv.x, wv.x,
         fmaf(hv.y, wv.y,
         fmaf(hv.z, wv.z,
         fmaf(hv.w, wv.w, acc))));
}

// ---------------- persistent fused 2-layer LSTM ----------------
// 256 blocks (1/CU via 122KB LDS) x 256 threads. Phase t: L1 step t, L2 step t-1.
// Block (bg,cg): batches b0..b0+15, m-cols m0..m0+7 (x4 gates x3 matmuls).
// Thread: b-pair (bp) x col-slot (g,ml); acc[2 b][3 mat]; K=512 serial.
__global__ __launch_bounds__(256, 1)
void lstm_fused(const float* __restrict__ pre, const float* __restrict__ WT,
                const float* __restrict__ b2, float* __restrict__ h1ring,
                float* __restrict__ h2all, unsigned* __restrict__ bar) {
  __shared__ float h1s[16 * 516];
  __shared__ float h2s[16 * 516];
  __shared__ float Wb[2 * 96 * 68];      // [buf][row j][64k + 4 pad]
  __shared__ float ex[3 * 16 * 4 * 9];   // [mat][b][gate][ml pad 9]

  const int tid = threadIdx.x;
  const int bg  = blockIdx.x >> 6;       // 0..3
  const int cg  = blockIdx.x & 63;       // 0..63
  const int b0  = bg * 16;
  const int m0  = cg * 8;

  const int bp   = tid >> 5;             // 0..7
  const int cs   = tid & 31;             // (g,ml)
  const int g    = cs >> 3, ml = cs & 7;
  const int b_lo = bp * 2;

  // phase-invariant W staging addresses (6 float4 slots per thread)
  const float* wsrc[6];
  int wdst[6];
#pragma unroll
  for (int s = 0; s < 6; ++s) {
    const int v  = tid + s * 256;
    const int j  = v >> 4, kq = v & 15;
    const int mt = j >> 5, jj = j & 31;
    const int gg = jj >> 3, mm = jj & 7;
    const int c  = gg * 512 + m0 + mm;
    wsrc[s] = WT + ((size_t)mt * Gg + c) * Hh + kq * 4;
    wdst[s] = j * 68 + kq * 4;
  }

  // gate-thread (tid<128) setup: owns (b0+eb, m0+eml); cell state in regs
  const int eb = tid >> 3, eml = tid & 7;
  float b2r0 = 0, b2r1 = 0, b2r2 = 0, b2r3 = 0;
  if (tid < 128) {
    b2r0 = b2[0 * 512 + m0 + eml];
    b2r1 = b2[1 * 512 + m0 + eml];
    b2r2 = b2[2 * 512 + m0 + eml];
    b2r3 = b2[3 * 512 + m0 + eml];
  }
  float c1r = 0.f, c2r = 0.f;

  for (int t = 0; t <= Tt; ++t) {
    // prefetch pre1 gate inputs (consumed in epilogue; latency hidden)
    float p0 = 0, p1 = 0, p2 = 0, p3 = 0;
    if (tid < 128 && t < Tt) {
      const float* pp = pre + ((size_t)(b0 + eb) * Tt + t) * Gg + m0 + eml;
      p0 = pp[0]; p1 = pp[512]; p2 = pp[1024]; p3 = pp[1536];
    }
    // stage h1[t-1], h2[t-2] and W chunk 0
    float4 wreg[6];
#pragma unroll
    for (int s = 0; s < 6; ++s) wreg[s] = *(const float4*)(wsrc[s]);
#pragma unroll
    for (int s = 0; s < 8; ++s) {
      const int v = tid + s * 256;
      const int row = v >> 7, c4 = (v & 127) * 4;
      float4 hv = make_float4(0.f, 0.f, 0.f, 0.f);
      if (t > 0)
        hv = *(const float4*)(h1ring +
              ((size_t)(((t - 1) & 1) * 64) + b0 + row) * 512 + c4);
      *(float4*)(&h1s[row * 516 + c4]) = hv;
      float4 h2v = make_float4(0.f, 0.f, 0.f, 0.f);
      if (t >= 2)
        h2v = *(const float4*)(h2all +
              ((size_t)(b0 + row) * Tt + (t - 2)) * 512 + c4);
      *(float4*)(&h2s[row * 516 + c4]) = h2v;
    }
#pragma unroll
    for (int s = 0; s < 6; ++s) *(float4*)(&Wb[wdst[s]]) = wreg[s];
    __syncthreads();

    // matmuls: acc[b][mat] over K=512 in 8 chunks of 64, W double-buffered
    float a00 = 0, a01 = 0, a02 = 0, a10 = 0, a11 = 0, a12 = 0;
    for (int ch = 0; ch < 8; ++ch) {
      const int cb = (ch & 1) * 6528;
      if (ch < 7) {
#pragma unroll
        for (int s = 0; s < 6; ++s)
          wreg[s] = *(const float4*)(wsrc[s] + (ch + 1) * 64);
      }
#pragma unroll
      for (int kj = 0; kj < 16; ++kj) {
        const int k = ch * 64 + kj * 4;
        const float4 w0 = *(const float4*)(&Wb[cb + cs * 68 + kj * 4]);
        const float4 w1 = *(const float4*)(&Wb[cb + (32 + cs) * 68 + kj * 4]);
        const float4 w2 = *(const float4*)(&Wb[cb + (64 + cs) * 68 + kj * 4]);
        const float4 hA = *(const float4*)(&h1s[b_lo * 516 + k]);
        const float4 hB = *(const float4*)(&h1s[(b_lo + 1) * 516 + k]);
        const float4 gA = *(const float4*)(&h2s[b_lo * 516 + k]);
        const float4 gB = *(const float4*)(&h2s[(b_lo + 1) * 516 + k]);
        a00 = dot4(a00, hA, w0); a01 = dot4(a01, hA, w1); a02 = dot4(a02, gA, w2);
        a10 = dot4(a10, hB, w0); a11 = dot4(a11, hB, w1); a12 = dot4(a12, gB, w2);
      }
      if (ch < 7) {
        const int nb = ((ch + 1) & 1) * 6528;
#pragma unroll
        for (int s = 0; s < 6; ++s) *(float4*)(&Wb[nb + wdst[s]]) = wreg[s];
      }
      __syncthreads();
    }

    // exchange partial gate sums
    ex[((0 * 16 + b_lo) * 4 + g) * 9 + ml]       = a00;
    ex[((1 * 16 + b_lo) * 4 + g) * 9 + ml]       = a01;
    ex[((2 * 16 + b_lo) * 4 + g) * 9 + ml]       = a02;
    ex[((0 * 16 + b_lo + 1) * 4 + g) * 9 + ml]   = a10;
    ex[((1 * 16 + b_lo + 1) * 4 + g) * 9 + ml]   = a11;
    ex[((2 * 16 + b_lo + 1) * 4 + g) * 9 + ml]   = a12;
    __syncthreads();

    // gate math: thread owns (b0+eb, m0+eml); c-state in registers
    if (tid < 128) {
      if (t < Tt) {
        const float gi = p0 + ex[((0 * 16 + eb) * 4 + 0) * 9 + eml];
        const float gj = p1 + ex[((0 * 16 + eb) * 4 + 1) * 9 + eml];
        const float gf = p2 + ex[((0 * 16 + eb) * 4 + 2) * 9 + eml];
        const float go = p3 + ex[((0 * 16 + eb) * 4 + 3) * 9 + eml];
        const float si = 1.f / (1.f + expf(-gi));
        const float sf = 1.f / (1.f + expf(-(gf + 1.f)));
        const float so = 1.f / (1.f + expf(-go));
        c1r = fmaf(c1r, sf, si * tanhf(gj));
        h1ring[((size_t)((t & 1) * 64) + b0 + eb) * 512 + m0 + eml] =
            tanhf(c1r) * so;
      }
      if (t >= 1) {
        const float gi = b2r0 + ex[((1 * 16 + eb) * 4 + 0) * 9 + eml]
                               + ex[((2 * 16 + eb) * 4 + 0) * 9 + eml];
        const float gj = b2r1 + ex[((1 * 16 + eb) * 4 + 1) * 9 + eml]
                               + ex[((2 * 16 + eb) * 4 + 1) * 9 + eml];
        const float gf = b2r2 + ex[((1 * 16 + eb) * 4 + 2) * 9 + eml]
                               + ex[((2 * 16 + eb) * 4 + 2) * 9 + eml];
        const float go = b2r3 + ex[((1 * 16 + eb) * 4 + 3) * 9 + eml]
                               + ex[((2 * 16 + eb) * 4 + 3) * 9 + eml];
        const float si = 1.f / (1.f + expf(-gi));
        const float sf = 1.f / (1.f + expf(-(gf + 1.f)));
        const float so = 1.f / (1.f + expf(-go));
        c2r = fmaf(c2r, sf, si * tanhf(gj));
        h2all[((size_t)(b0 + eb) * Tt + (t - 1)) * 512 + m0 + eml] =
            tanhf(c2r) * so;
      }
    }

    // grid barrier (device-scope). Release/acquire cache ops executed by ALL
    // waves (per-XCD L2 non-coherence — G16); tid0 does the atomic handshake.
    if (t < Tt) {
      __syncthreads();      // all block writes issued (vmcnt drained at barrier)
      __threadfence();      // release: writeback L1/L2 (every wave)
      if (tid == 0) {
        __hip_atomic_fetch_add(bar, 1u, __ATOMIC_ACQ_REL,
                               __HIP_MEMORY_SCOPE_AGENT);
        const unsigned tgt = (unsigned)(t + 1) * 256u;
        while (__hip_atomic_load(bar, __ATOMIC_ACQUIRE,
                                 __HIP_MEMORY_SCOPE_AGENT) < tgt)
          __builtin_amdgcn_s_sleep(2);
      }
      __syncthreads();
      __threadfence();      // acquire: invalidate stale lines (every wave)
    }
  }
}

// ---------------- Output projection + softmax + CE ----------------
__global__ __launch_bounds__(128)
void proj_softmax(const float* __restrict__ h2, const float* __restrict__ Wout,
                  const float* __restrict__ bout, const int* __restrict__ labels,
                  float* __restrict__ preds, float* __restrict__ ce) {
  __shared__ float hs[8][Hh];
  __shared__ float wred[2][2];
  const int tid = threadIdx.x;
  const int wid = tid >> 6;
  const int r0  = blockIdx.x * 8;

  for (int i = tid; i < 8 * (Hh / 4); i += 128) {
    const int row = i >> 7;
    const int c4  = i & 127;
    ((float4*)hs[row])[c4] =
        ((const float4*)(h2 + ((size_t)(r0 + row) * Hh)))[c4];
  }
  __syncthreads();

  const bool act = (tid < Cc);
  float acc[8];
  {
    const float bj = act ? bout[tid] : 0.f;
#pragma unroll
    for (int i = 0; i < 8; ++i) acc[i] = bj;
  }
  if (act) {
#pragma unroll 4
    for (int k = 0; k < Hh; ++k) {
      const float w = Wout[k * Cc + tid];
#pragma unroll
      for (int i = 0; i < 8; ++i) acc[i] = fmaf(hs[i][k], w, acc[i]);
    }
  }

  for (int row = 0; row < 8; ++row) {
    const float v = act ? acc[row] : -INFINITY;
    float mw = v;
#pragma unroll
    for (int off = 32; off > 0; off >>= 1) mw = fmaxf(mw, __shfl_xor(mw, off));
    if ((tid & 63) == 0) wred[0][wid] = mw;
    __syncthreads();
    const float mx = fmaxf(wred[0][0], wred[0][1]);
    const float e = act ? expf(v - mx) : 0.f;
    float sw = e;
#pragma unroll
    for (int off = 32; off > 0; off >>= 1) sw += __shfl_xor(sw, off);
    if ((tid & 63) == 0) wred[1][wid] = sw;
    __syncthreads();
    const float sum = wred[1][0] + wred[1][1];
    if (act) preds[(size_t)(r0 + row) * Cc + tid] = e / sum;
    const int lab = labels[r0 + row];
    if (tid == lab) ce[r0 + row] = logf(sum) + mx - v;
    __syncthreads();
  }
}

__global__ __launch_bounds__(256)
void reduce_cost(const float* __restrict__ ce, float* __restrict__ out) {
  __shared__ float red[256];
  const int tid = threadIdx.x;
  float s = 0.f;
  for (int i = tid; i < ROWS; i += 256) s += ce[i];
  red[tid] = s;
  __syncthreads();
  for (int st = 128; st > 0; st >>= 1) {
    if (tid < st) red[tid] += red[tid + st];
    __syncthreads();
  }
  if (tid == 0) out[0] = red[0] / (float)Bb;
}

// ---------------- launch ----------------
extern "C" void kernel_launch(void* const* d_in, const int* in_sizes, int n_in,
                              void* d_out, int out_size, void* d_ws, size_t ws_size,
                              hipStream_t stream) {
  const float* inputs = (const float*)d_in[0];
  const int*   labels = (const int*)d_in[1];
  const float* W1     = (const float*)d_in[2];
  const float* b1     = (const float*)d_in[3];
  const float* W2     = (const float*)d_in[4];
  const float* b2     = (const float*)d_in[5];
  const float* Wout   = (const float*)d_in[6];
  const float* bout   = (const float*)d_in[7];
  float* out = (float*)d_out;

  float* ws     = (float*)d_ws;
  float* pre    = ws;                              // ROWS*Gg
  float* h2all  = pre    + (size_t)ROWS * Gg;      // ROWS*Hh
  float* h1ring = h2all  + (size_t)ROWS * Hh;      // 2*64*512
  float* WT     = h1ring + 2 * 64 * 512;           // 3*Gg*Hh
  float* ceb    = WT     + (size_t)3 * Gg * Hh;    // ROWS
  unsigned* bar = (unsigned*)(ceb + ROWS + 64);

  init_bar<<<1, 64, 0, stream>>>(bar);
  transposeW<<<dim3(16, 64, 3), dim3(32, 8), 0, stream>>>(W1, W2, WT);

  // Layer 1 input projection: pre = X @ W1[0:D,:] + b1
  sgemm_bias<<<dim3(Gg / BN, ROWS / BM), dim3(256), 0, stream>>>(
      inputs, W1, b1, pre, ROWS, Gg, Dd);

  // Entire recurrence (both layers, GEMM2 folded in), one dispatch
  lstm_fused<<<256, 256, 0, stream>>>(pre, WT, b2, h1ring, h2all, bar);

  proj_softmax<<<ROWS / 8, 128, 0, stream>>>(h2all, Wout, bout, labels, out, ceb);
  reduce_cost<<<1, 256, 0, stream>>>(ceb, out + (size_t)ROWS * Cc);
}

// Round 5
// 2739.560 us; speedup vs baseline: 4.3044x; 4.3044x over previous
//
#include <hip/hip_runtime.h>
#include <cmath>

// Problem constants
#define Bb   64
#define Tt   128
#define Dd   2048
#define Hh   512
#define Gg   2048      // 4*H
#define Cc   101
#define ROWS 8192      // B*T

// ---------------- SGEMM (fp32, vector ALU) ----------------
#define BM 128
#define BN 128
#define BK 16

__global__ __launch_bounds__(256)
void sgemm_bias(const float* __restrict__ A, const float* __restrict__ B,
                const float* __restrict__ bias, float* __restrict__ C,
                int M, int N, int K) {
  __shared__ float As[BK][BM];
  __shared__ float Bs[BK][BN];
  const int tid  = threadIdx.x;
  const int bn   = blockIdx.x;
  const int bm   = blockIdx.y;
  const int row0 = bm * BM, col0 = bn * BN;
  const int tr = (tid >> 4) << 3;
  const int tc = (tid & 15) << 3;

  float acc[8][8];
#pragma unroll
  for (int i = 0; i < 8; ++i)
#pragma unroll
    for (int j = 0; j < 8; ++j) acc[i][j] = 0.f;

  const int arow = tid >> 1;
  const int acol = (tid & 1) << 3;
  const int brow = tid >> 4;
  const int bcol = (tid & 15) << 3;
  const float* Ap = A + (size_t)(row0 + arow) * K + acol;
  const float* Bp = B + (size_t)brow * N + (col0 + bcol);

  for (int k0 = 0; k0 < K; k0 += BK) {
    const float4 a0 = *(const float4*)(Ap + k0);
    const float4 a1 = *(const float4*)(Ap + k0 + 4);
    const float4 bv0 = *(const float4*)(Bp + (size_t)k0 * N);
    const float4 bv1 = *(const float4*)(Bp + (size_t)k0 * N + 4);
    As[acol + 0][arow] = a0.x;
    As[acol + 1][arow] = a0.y;
    As[acol + 2][arow] = a0.z;
    As[acol + 3][arow] = a0.w;
    As[acol + 4][arow] = a1.x;
    As[acol + 5][arow] = a1.y;
    As[acol + 6][arow] = a1.z;
    As[acol + 7][arow] = a1.w;
    *(float4*)(&Bs[brow][bcol])     = bv0;
    *(float4*)(&Bs[brow][bcol + 4]) = bv1;
    __syncthreads();
#pragma unroll
    for (int k = 0; k < BK; ++k) {
      float a[8], b[8];
      *(float4*)(a)     = *(const float4*)(&As[k][tr]);
      *(float4*)(a + 4) = *(const float4*)(&As[k][tr + 4]);
      *(float4*)(b)     = *(const float4*)(&Bs[k][tc]);
      *(float4*)(b + 4) = *(const float4*)(&Bs[k][tc + 4]);
#pragma unroll
      for (int i = 0; i < 8; ++i)
#pragma unroll
        for (int j = 0; j < 8; ++j)
          acc[i][j] = fmaf(a[i], b[j], acc[i][j]);
    }
    __syncthreads();
  }

  float bj[8];
#pragma unroll
  for (int j = 0; j < 8; ++j) bj[j] = bias[col0 + tc + j];
#pragma unroll
  for (int i = 0; i < 8; ++i) {
    float* Cp = C + (size_t)(row0 + tr + i) * N + (col0 + tc);
    float4 o0, o1;
    o0.x = acc[i][0] + bj[0]; o0.y = acc[i][1] + bj[1];
    o0.z = acc[i][2] + bj[2]; o0.w = acc[i][3] + bj[3];
    o1.x = acc[i][4] + bj[4]; o1.y = acc[i][5] + bj[5];
    o1.z = acc[i][6] + bj[6]; o1.w = acc[i][7] + bj[7];
    *(float4*)(Cp)     = o0;
    *(float4*)(Cp + 4) = o1;
  }
}

// ---------------- weight transpose ----------------
// WT1[c][k] (c 2048, k 512)  <- W1 rows D..D+511
// WT2[c][k] (c 2048, k 1024) <- [W2 rows 0..511 ; W2 rows 512..1023]
__global__ __launch_bounds__(256)
void transposeW(const float* __restrict__ W1, const float* __restrict__ W2,
                float* __restrict__ WT1, float* __restrict__ WT2) {
  __shared__ float tl[32][33];
  const int tx = threadIdx.x, ty = threadIdx.y;   // 32, 8
  const int k0 = blockIdx.x * 32, c0 = blockIdx.y * 32, mat = blockIdx.z;
  const float* src;
  float* dst;
  int dstK, koff;
  if (mat == 0)      { src = W1 + (size_t)Dd * Gg; dst = WT1; dstK = 512;  koff = 0; }
  else if (mat == 1) { src = W2;                   dst = WT2; dstK = 1024; koff = 0; }
  else               { src = W2 + (size_t)Hh * Gg; dst = WT2; dstK = 1024; koff = 512; }
#pragma unroll
  for (int j = 0; j < 4; ++j)
    tl[ty + j * 8][tx] = src[(size_t)(k0 + ty + j * 8) * Gg + (c0 + tx)];
  __syncthreads();
#pragma unroll
  for (int j = 0; j < 4; ++j)
    dst[(size_t)(c0 + ty + j * 8) * dstK + koff + k0 + tx] = tl[tx][ty + j * 8];
}

__device__ __forceinline__ float dot4(float acc, float4 hv, float4 wv) {
  return fmaf(hv.x, wv.x,
         fmaf(hv.y, wv.y,
         fmaf(hv.z, wv.z,
         fmaf(hv.w, wv.w, acc))));
}

__device__ __forceinline__ float sigm(float x) { return 1.f / (1.f + expf(-x)); }

// ---------------- fused two-layer step (one launch per phase) ----------------
// Phase t: blocks 0..127   = L1 step t      (16 b x 64 cols, K=512)
//          blocks 128..383 = L2 step t-1    ( 8 b x 64 cols, K=1024: [h1;h2]@W2)
// 256 thr = 16 col-quads(q) x 16 K-splits(ks). Butterfly-reduce over ks lanes.
__global__ __launch_bounds__(256, 2)
void fused_step(const float* __restrict__ pre, const float* __restrict__ WT1,
                const float* __restrict__ WT2, const float* __restrict__ b2,
                float* __restrict__ h1ring, float* __restrict__ h2all,
                float* __restrict__ c1, float* __restrict__ c2, int t) {
  __shared__ float hs[8256];       // L1: [16][516]  L2: [8][1032]
  __shared__ float ex[64 * 17];    // [col j][b]
  const int tid = threadIdx.x;
  const int q   = tid >> 4;        // 0..15
  const int ks  = tid & 15;        // 0..15
  const int g   = q >> 2;          // gate 0..3
  const int mq  = (q & 3) * 4;     // col-quad offset within gate's 16 m's

  if (blockIdx.x < 128) {
    // ---------------- Layer 1, step t ----------------
    if (t >= Tt) return;
    const int bg = blockIdx.x >> 5, cg = blockIdx.x & 31;
    const int b0 = bg * 16, m0 = cg * 16;
    const float* Wbase = WT1 + (size_t)(g * 512 + m0 + mq) * 512;

    float acc[16][4];
#pragma unroll
    for (int b = 0; b < 16; ++b)
#pragma unroll
      for (int c = 0; c < 4; ++c) acc[b][c] = 0.f;

    if (t > 0) {
      const float* hsrc = h1ring + ((size_t)(((t - 1) & 1) * 64 + b0)) * 512;
#pragma unroll
      for (int s = 0; s < 8; ++s) {
        const int v = tid + s * 256;
        const int row = v >> 7, f4 = v & 127;
        *(float4*)(&hs[row * 516 + f4 * 4]) =
            *(const float4*)(hsrc + row * 512 + f4 * 4);
      }
      __syncthreads();
#pragma unroll
      for (int it = 0; it < 8; ++it) {
        const int k = it * 64 + ks * 4;
        const float4 w0 = *(const float4*)(Wbase + k);
        const float4 w1 = *(const float4*)(Wbase + 512 + k);
        const float4 w2 = *(const float4*)(Wbase + 1024 + k);
        const float4 w3 = *(const float4*)(Wbase + 1536 + k);
#pragma unroll
        for (int b = 0; b < 16; ++b) {
          const float4 hv = *(const float4*)(&hs[b * 516 + k]);
          acc[b][0] = dot4(acc[b][0], hv, w0);
          acc[b][1] = dot4(acc[b][1], hv, w1);
          acc[b][2] = dot4(acc[b][2], hv, w2);
          acc[b][3] = dot4(acc[b][3], hv, w3);
        }
      }
    }
    // butterfly-reduce over the 16 ks lanes (consecutive lanes in wave)
#pragma unroll
    for (int b = 0; b < 16; ++b)
#pragma unroll
      for (int c = 0; c < 4; ++c) {
        float v = acc[b][c];
        v += __shfl_xor(v, 1); v += __shfl_xor(v, 2);
        v += __shfl_xor(v, 4); v += __shfl_xor(v, 8);
        acc[b][c] = v;
      }
    // lane ks extracts b == ks (compile-time index, predicated)
#pragma unroll
    for (int b = 0; b < 16; ++b)
      if (ks == b) {
#pragma unroll
        for (int c = 0; c < 4; ++c) ex[(q * 4 + c) * 17 + b] = acc[b][c];
      }
    __syncthreads();

    // epilogue: 256 outputs, one per thread
    {
      const int b = tid >> 4, ml = tid & 15;
      const size_t prow = ((size_t)(b0 + b) * Tt + t) * Gg + m0 + ml;
      const float gi = pre[prow]        + ex[(0 * 16 + ml) * 17 + b];
      const float gj = pre[prow + 512]  + ex[(1 * 16 + ml) * 17 + b];
      const float gf = pre[prow + 1024] + ex[(2 * 16 + ml) * 17 + b];
      const float go = pre[prow + 1536] + ex[(3 * 16 + ml) * 17 + b];
      const int ci = (b0 + b) * Hh + m0 + ml;
      const float cp = (t > 0) ? c1[ci] : 0.f;
      const float nc = fmaf(cp, sigm(gf + 1.f), sigm(gi) * tanhf(gj));
      c1[ci] = nc;
      h1ring[((size_t)((t & 1) * 64 + b0 + b)) * 512 + m0 + ml] =
          tanhf(nc) * sigm(go);
    }
  } else {
    // ---------------- Layer 2, step t-1 ----------------
    if (t < 1) return;
    const int idx = blockIdx.x - 128;
    const int bg = idx >> 5, cg = idx & 31;
    const int b0 = bg * 8, m0 = cg * 16;
    const float* Wbase = WT2 + (size_t)(g * 512 + m0 + mq) * 1024;

    float acc[8][4];
#pragma unroll
    for (int b = 0; b < 8; ++b)
#pragma unroll
      for (int c = 0; c < 4; ++c) acc[b][c] = 0.f;

    // stage [h1[t-1] ; h2[t-2]] rows b0..b0+7 -> hs[8][1032]
    const float* h1src = h1ring + ((size_t)(((t - 1) & 1) * 64 + b0)) * 512;
#pragma unroll
    for (int s = 0; s < 8; ++s) {
      const int v = tid + s * 256;
      const int row = v >> 8, f4 = v & 255;
      float4 hv;
      if (f4 < 128) {
        hv = *(const float4*)(h1src + row * 512 + f4 * 4);
      } else if (t >= 2) {
        hv = *(const float4*)(h2all +
              ((size_t)(b0 + row) * Tt + (t - 2)) * 512 + (f4 - 128) * 4);
      } else {
        hv = make_float4(0.f, 0.f, 0.f, 0.f);
      }
      *(float4*)(&hs[row * 1032 + f4 * 4]) = hv;
    }
    __syncthreads();
#pragma unroll
    for (int it = 0; it < 16; ++it) {
      const int k = it * 64 + ks * 4;
      const float4 w0 = *(const float4*)(Wbase + k);
      const float4 w1 = *(const float4*)(Wbase + 1024 + k);
      const float4 w2 = *(const float4*)(Wbase + 2048 + k);
      const float4 w3 = *(const float4*)(Wbase + 3072 + k);
#pragma unroll
      for (int b = 0; b < 8; ++b) {
        const float4 hv = *(const float4*)(&hs[b * 1032 + k]);
        acc[b][0] = dot4(acc[b][0], hv, w0);
        acc[b][1] = dot4(acc[b][1], hv, w1);
        acc[b][2] = dot4(acc[b][2], hv, w2);
        acc[b][3] = dot4(acc[b][3], hv, w3);
      }
    }
#pragma unroll
    for (int b = 0; b < 8; ++b)
#pragma unroll
      for (int c = 0; c < 4; ++c) {
        float v = acc[b][c];
        v += __shfl_xor(v, 1); v += __shfl_xor(v, 2);
        v += __shfl_xor(v, 4); v += __shfl_xor(v, 8);
        acc[b][c] = v;
      }
#pragma unroll
    for (int b = 0; b < 8; ++b)
      if (ks == b) {
#pragma unroll
        for (int c = 0; c < 4; ++c) ex[(q * 4 + c) * 17 + b] = acc[b][c];
      }
    __syncthreads();

    if (tid < 128) {
      const int b = tid >> 4, ml = tid & 15;
      const float gi = b2[0 * 512 + m0 + ml] + ex[(0 * 16 + ml) * 17 + b];
      const float gj = b2[1 * 512 + m0 + ml] + ex[(1 * 16 + ml) * 17 + b];
      const float gf = b2[2 * 512 + m0 + ml] + ex[(2 * 16 + ml) * 17 + b];
      const float go = b2[3 * 512 + m0 + ml] + ex[(3 * 16 + ml) * 17 + b];
      const int ci = (b0 + b) * Hh + m0 + ml;
      const float cp = (t >= 2) ? c2[ci] : 0.f;
      const float nc = fmaf(cp, sigm(gf + 1.f), sigm(gi) * tanhf(gj));
      c2[ci] = nc;
      h2all[((size_t)(b0 + b) * Tt + (t - 1)) * 512 + m0 + ml] =
          tanhf(nc) * sigm(go);
    }
  }
}

// ---------------- Output projection + softmax + CE ----------------
__global__ __launch_bounds__(128)
void proj_softmax(const float* __restrict__ h2, const float* __restrict__ Wout,
                  const float* __restrict__ bout, const int* __restrict__ labels,
                  float* __restrict__ preds, float* __restrict__ ce) {
  __shared__ float hs[8][Hh];
  __shared__ float wred[2][2];
  const int tid = threadIdx.x;
  const int wid = tid >> 6;
  const int r0  = blockIdx.x * 8;

  for (int i = tid; i < 8 * (Hh / 4); i += 128) {
    const int row = i >> 7;
    const int c4  = i & 127;
    ((float4*)hs[row])[c4] =
        ((const float4*)(h2 + ((size_t)(r0 + row) * Hh)))[c4];
  }
  __syncthreads();

  const bool act = (tid < Cc);
  float acc[8];
  {
    const float bj = act ? bout[tid] : 0.f;
#pragma unroll
    for (int i = 0; i < 8; ++i) acc[i] = bj;
  }
  if (act) {
#pragma unroll 4
    for (int k = 0; k < Hh; ++k) {
      const float w = Wout[k * Cc + tid];
#pragma unroll
      for (int i = 0; i < 8; ++i) acc[i] = fmaf(hs[i][k], w, acc[i]);
    }
  }

  for (int row = 0; row < 8; ++row) {
    const float v = act ? acc[row] : -INFINITY;
    float mw = v;
#pragma unroll
    for (int off = 32; off > 0; off >>= 1) mw = fmaxf(mw, __shfl_xor(mw, off));
    if ((tid & 63) == 0) wred[0][wid] = mw;
    __syncthreads();
    const float mx = fmaxf(wred[0][0], wred[0][1]);
    const float e = act ? expf(v - mx) : 0.f;
    float sw = e;
#pragma unroll
    for (int off = 32; off > 0; off >>= 1) sw += __shfl_xor(sw, off);
    if ((tid & 63) == 0) wred[1][wid] = sw;
    __syncthreads();
    const float sum = wred[1][0] + wred[1][1];
    if (act) preds[(size_t)(r0 + row) * Cc + tid] = e / sum;
    const int lab = labels[r0 + row];
    if (tid == lab) ce[r0 + row] = logf(sum) + mx - v;
    __syncthreads();
  }
}

__global__ __launch_bounds__(256)
void reduce_cost(const float* __restrict__ ce, float* __restrict__ out) {
  __shared__ float red[256];
  const int tid = threadIdx.x;
  float s = 0.f;
  for (int i = tid; i < ROWS; i += 256) s += ce[i];
  red[tid] = s;
  __syncthreads();
  for (int st = 128; st > 0; st >>= 1) {
    if (tid < st) red[tid] += red[tid + st];
    __syncthreads();
  }
  if (tid == 0) out[0] = red[0] / (float)Bb;
}

// ---------------- launch ----------------
extern "C" void kernel_launch(void* const* d_in, const int* in_sizes, int n_in,
                              void* d_out, int out_size, void* d_ws, size_t ws_size,
                              hipStream_t stream) {
  const float* inputs = (const float*)d_in[0];
  const int*   labels = (const int*)d_in[1];
  const float* W1     = (const float*)d_in[2];
  const float* b1     = (const float*)d_in[3];
  const float* W2     = (const float*)d_in[4];
  const float* b2     = (const float*)d_in[5];
  const float* Wout   = (const float*)d_in[6];
  const float* bout   = (const float*)d_in[7];
  float* out = (float*)d_out;

  float* ws     = (float*)d_ws;
  float* pre    = ws;                              // ROWS*Gg        (16M)
  float* h2all  = pre    + (size_t)ROWS * Gg;      // ROWS*Hh        (4M)
  float* h1ring = h2all  + (size_t)ROWS * Hh;      // 2*64*512
  float* c1     = h1ring + 2 * 64 * 512;           // 64*512
  float* c2     = c1     + (size_t)Bb * Hh;        // 64*512
  float* WT1    = c2     + (size_t)Bb * Hh;        // 2048*512       (1M)
  float* WT2    = WT1    + (size_t)Gg * Hh;        // 2048*1024      (2M)
  float* ceb    = WT2    + (size_t)Gg * 2 * Hh;    // ROWS

  transposeW<<<dim3(16, 64, 3), dim3(32, 8), 0, stream>>>(W1, W2, WT1, WT2);

  // Layer 1 input projection: pre = X @ W1[0:D,:] + b1
  sgemm_bias<<<dim3(Gg / BN, ROWS / BM), dim3(256), 0, stream>>>(
      inputs, W1, b1, pre, ROWS, Gg, Dd);

  // Recurrence: phase t = L1 step t + L2 step t-1 (GEMM2 folded into L2's K=1024)
  for (int t = 0; t <= Tt; ++t)
    fused_step<<<384, 256, 0, stream>>>(pre, WT1, WT2, b2,
                                        h1ring, h2all, c1, c2, t);

  proj_softmax<<<ROWS / 8, 128, 0, stream>>>(h2all, Wout, bout, labels, out, ceb);
  reduce_cost<<<1, 256, 0, stream>>>(ceb, out + (size_t)ROWS * Cc);
}

// Round 6
// 2230.991 us; speedup vs baseline: 5.2856x; 1.2280x over previous
//
#include <hip/hip_runtime.h>
#include <cmath>

// Problem constants
#define Bb   64
#define Tt   128
#define Dd   2048
#define Hh   512
#define Gg   2048      // 4*H
#define Cc   101
#define ROWS 8192      // B*T

typedef unsigned short u16;
typedef __attribute__((ext_vector_type(8))) short bf16x8;
typedef __attribute__((ext_vector_type(4))) float f32x4;

// ---------------- bf16 hi/lo split helpers ----------------
__device__ __forceinline__ u16 bf16rne(float x) {
  unsigned u = __float_as_uint(x);
  unsigned r = (u + 0x7fffu + ((u >> 16) & 1u)) >> 16;
  return (u16)r;
}
__device__ __forceinline__ void split_bf16(float x, u16& h, u16& l) {
  h = bf16rne(x);
  l = bf16rne(x - __uint_as_float(((unsigned)h) << 16));
}

// X [ROWS x Dd] fp32 -> Xhi, Xlo bf16 (same layout)
__global__ __launch_bounds__(256)
void convert_hilo(const float* __restrict__ src, u16* __restrict__ hi,
                  u16* __restrict__ lo, int n4) {
  for (int i = blockIdx.x * 256 + threadIdx.x; i < n4; i += gridDim.x * 256) {
    const float4 v = ((const float4*)src)[i];
    ushort4 h, l;
    split_bf16(v.x, h.x, l.x);
    split_bf16(v.y, h.y, l.y);
    split_bf16(v.z, h.z, l.z);
    split_bf16(v.w, h.w, l.w);
    ((ushort4*)hi)[i] = h;
    ((ushort4*)lo)[i] = l;
  }
}

// W1 top [Dd x Gg] -> W1T hi/lo [Gg x Dd] bf16
__global__ __launch_bounds__(256)
void convertT_w1(const float* __restrict__ W1, u16* __restrict__ Th,
                 u16* __restrict__ Tl) {
  __shared__ float tl[32][33];
  const int tx = threadIdx.x, ty = threadIdx.y;   // 32, 8
  const int k0 = blockIdx.x * 32, c0 = blockIdx.y * 32;
#pragma unroll
  for (int j = 0; j < 4; ++j)
    tl[ty + j * 8][tx] = W1[(size_t)(k0 + ty + j * 8) * Gg + (c0 + tx)];
  __syncthreads();
#pragma unroll
  for (int j = 0; j < 4; ++j) {
    const float v = tl[tx][ty + j * 8];
    u16 h, l;
    split_bf16(v, h, l);
    const size_t o = (size_t)(c0 + ty + j * 8) * Dd + (k0 + tx);
    Th[o] = h;
    Tl[o] = l;
  }
}

// ---------------- MFMA bf16x3 GEMM: pre = X @ W1 + b1 ----------------
// 128x128 tile, BK=32, 256 thr = 4 waves (2x2), each wave 64x64 = 4x4 frags.
// acc += Ahi*Bhi + Ahi*Blo + Alo*Bhi  (fp32 accum; ~17-bit effective mantissa)
__global__ __launch_bounds__(256)
void gemm1_mfma(const u16* __restrict__ Ah, const u16* __restrict__ Al,
                const u16* __restrict__ Bh, const u16* __restrict__ Bl,
                const float* __restrict__ bias, float* __restrict__ C) {
  __shared__ u16 Ash[128][40];   // pad 40: frag reads <=2-way bank alias
  __shared__ u16 Asl[128][40];
  __shared__ u16 Bsh[128][40];
  __shared__ u16 Bsl[128][40];
  const int tid  = threadIdx.x;
  const int lane = tid & 63, wave = tid >> 6;
  const int wm = wave >> 1, wn = wave & 1;
  const int l15 = lane & 15, k8 = (lane >> 4) * 8, r4 = (lane >> 4) * 4;
  const int row0 = blockIdx.y * 128, col0 = blockIdx.x * 128;
  const int srow = tid >> 1, sk = (tid & 1) * 16;

  const u16* pAh = Ah + (size_t)(row0 + srow) * Dd + sk;
  const u16* pAl = Al + (size_t)(row0 + srow) * Dd + sk;
  const u16* pBh = Bh + (size_t)(col0 + srow) * Dd + sk;
  const u16* pBl = Bl + (size_t)(col0 + srow) * Dd + sk;

  f32x4 acc[4][4];
#pragma unroll
  for (int i = 0; i < 4; ++i)
#pragma unroll
    for (int j = 0; j < 4; ++j) acc[i][j] = (f32x4){0.f, 0.f, 0.f, 0.f};

  for (int k0 = 0; k0 < Dd; k0 += 32) {
    *(bf16x8*)(&Ash[srow][sk])     = *(const bf16x8*)(pAh + k0);
    *(bf16x8*)(&Ash[srow][sk + 8]) = *(const bf16x8*)(pAh + k0 + 8);
    *(bf16x8*)(&Asl[srow][sk])     = *(const bf16x8*)(pAl + k0);
    *(bf16x8*)(&Asl[srow][sk + 8]) = *(const bf16x8*)(pAl + k0 + 8);
    *(bf16x8*)(&Bsh[srow][sk])     = *(const bf16x8*)(pBh + k0);
    *(bf16x8*)(&Bsh[srow][sk + 8]) = *(const bf16x8*)(pBh + k0 + 8);
    *(bf16x8*)(&Bsl[srow][sk])     = *(const bf16x8*)(pBl + k0);
    *(bf16x8*)(&Bsl[srow][sk + 8]) = *(const bf16x8*)(pBl + k0 + 8);
    __syncthreads();

    bf16x8 afh[4], afl[4], bfh[4], bfl[4];
#pragma unroll
    for (int mt = 0; mt < 4; ++mt) {
      afh[mt] = *(const bf16x8*)(&Ash[wm * 64 + mt * 16 + l15][k8]);
      afl[mt] = *(const bf16x8*)(&Asl[wm * 64 + mt * 16 + l15][k8]);
    }
#pragma unroll
    for (int nt = 0; nt < 4; ++nt) {
      bfh[nt] = *(const bf16x8*)(&Bsh[wn * 64 + nt * 16 + l15][k8]);
      bfl[nt] = *(const bf16x8*)(&Bsl[wn * 64 + nt * 16 + l15][k8]);
    }
#pragma unroll
    for (int mt = 0; mt < 4; ++mt)
#pragma unroll
      for (int nt = 0; nt < 4; ++nt) {
        acc[mt][nt] = __builtin_amdgcn_mfma_f32_16x16x32_bf16(
            afh[mt], bfh[nt], acc[mt][nt], 0, 0, 0);
        acc[mt][nt] = __builtin_amdgcn_mfma_f32_16x16x32_bf16(
            afh[mt], bfl[nt], acc[mt][nt], 0, 0, 0);
        acc[mt][nt] = __builtin_amdgcn_mfma_f32_16x16x32_bf16(
            afl[mt], bfh[nt], acc[mt][nt], 0, 0, 0);
      }
    __syncthreads();
  }

  // epilogue: C[row][col], col = l15-owned, rows = r4+r
#pragma unroll
  for (int nt = 0; nt < 4; ++nt) {
    const int col = col0 + wn * 64 + nt * 16 + l15;
    const float bj = bias[col];
#pragma unroll
    for (int mt = 0; mt < 4; ++mt) {
      float* Cp = C + (size_t)(row0 + wm * 64 + mt * 16 + r4) * Gg + col;
#pragma unroll
      for (int r = 0; r < 4; ++r)
        Cp[(size_t)r * Gg] = acc[mt][nt][r] + bj;
    }
  }
}

// ---------------- SGEMM (fp32 fallback if ws too small) ----------------
#define BM 128
#define BN 128
#define BK 16

__global__ __launch_bounds__(256)
void sgemm_bias(const float* __restrict__ A, const float* __restrict__ B,
                const float* __restrict__ bias, float* __restrict__ C,
                int M, int N, int K) {
  __shared__ float As[BK][BM];
  __shared__ float Bs[BK][BN];
  const int tid  = threadIdx.x;
  const int bn   = blockIdx.x;
  const int bm   = blockIdx.y;
  const int row0 = bm * BM, col0 = bn * BN;
  const int tr = (tid >> 4) << 3;
  const int tc = (tid & 15) << 3;

  float acc[8][8];
#pragma unroll
  for (int i = 0; i < 8; ++i)
#pragma unroll
    for (int j = 0; j < 8; ++j) acc[i][j] = 0.f;

  const int arow = tid >> 1;
  const int acol = (tid & 1) << 3;
  const int brow = tid >> 4;
  const int bcol = (tid & 15) << 3;
  const float* Ap = A + (size_t)(row0 + arow) * K + acol;
  const float* Bp = B + (size_t)brow * N + (col0 + bcol);

  for (int k0 = 0; k0 < K; k0 += BK) {
    const float4 a0 = *(const float4*)(Ap + k0);
    const float4 a1 = *(const float4*)(Ap + k0 + 4);
    const float4 bv0 = *(const float4*)(Bp + (size_t)k0 * N);
    const float4 bv1 = *(const float4*)(Bp + (size_t)k0 * N + 4);
    As[acol + 0][arow] = a0.x;
    As[acol + 1][arow] = a0.y;
    As[acol + 2][arow] = a0.z;
    As[acol + 3][arow] = a0.w;
    As[acol + 4][arow] = a1.x;
    As[acol + 5][arow] = a1.y;
    As[acol + 6][arow] = a1.z;
    As[acol + 7][arow] = a1.w;
    *(float4*)(&Bs[brow][bcol])     = bv0;
    *(float4*)(&Bs[brow][bcol + 4]) = bv1;
    __syncthreads();
#pragma unroll
    for (int k = 0; k < BK; ++k) {
      float a[8], b[8];
      *(float4*)(a)     = *(const float4*)(&As[k][tr]);
      *(float4*)(a + 4) = *(const float4*)(&As[k][tr + 4]);
      *(float4*)(b)     = *(const float4*)(&Bs[k][tc]);
      *(float4*)(b + 4) = *(const float4*)(&Bs[k][tc + 4]);
#pragma unroll
      for (int i = 0; i < 8; ++i)
#pragma unroll
        for (int j = 0; j < 8; ++j)
          acc[i][j] = fmaf(a[i], b[j], acc[i][j]);
    }
    __syncthreads();
  }

  float bj[8];
#pragma unroll
  for (int j = 0; j < 8; ++j) bj[j] = bias[col0 + tc + j];
#pragma unroll
  for (int i = 0; i < 8; ++i) {
    float* Cp = C + (size_t)(row0 + tr + i) * N + (col0 + tc);
    float4 o0, o1;
    o0.x = acc[i][0] + bj[0]; o0.y = acc[i][1] + bj[1];
    o0.z = acc[i][2] + bj[2]; o0.w = acc[i][3] + bj[3];
    o1.x = acc[i][4] + bj[4]; o1.y = acc[i][5] + bj[5];
    o1.z = acc[i][6] + bj[6]; o1.w = acc[i][7] + bj[7];
    *(float4*)(Cp)     = o0;
    *(float4*)(Cp + 4) = o1;
  }
}

// ---------------- weight transpose (fp32, for recurrence) ----------------
// WT1[c][k] (c 2048, k 512)  <- W1 rows D..D+511
// WT2[c][k] (c 2048, k 1024) <- [W2 rows 0..511 ; W2 rows 512..1023]
__global__ __launch_bounds__(256)
void transposeW(const float* __restrict__ W1, const float* __restrict__ W2,
                float* __restrict__ WT1, float* __restrict__ WT2) {
  __shared__ float tl[32][33];
  const int tx = threadIdx.x, ty = threadIdx.y;   // 32, 8
  const int k0 = blockIdx.x * 32, c0 = blockIdx.y * 32, mat = blockIdx.z;
  const float* src;
  float* dst;
  int dstK, koff;
  if (mat == 0)      { src = W1 + (size_t)Dd * Gg; dst = WT1; dstK = 512;  koff = 0; }
  else if (mat == 1) { src = W2;                   dst = WT2; dstK = 1024; koff = 0; }
  else               { src = W2 + (size_t)Hh * Gg; dst = WT2; dstK = 1024; koff = 512; }
#pragma unroll
  for (int j = 0; j < 4; ++j)
    tl[ty + j * 8][tx] = src[(size_t)(k0 + ty + j * 8) * Gg + (c0 + tx)];
  __syncthreads();
#pragma unroll
  for (int j = 0; j < 4; ++j)
    dst[(size_t)(c0 + ty + j * 8) * dstK + koff + k0 + tx] = tl[tx][ty + j * 8];
}

__device__ __forceinline__ float dot4(float acc, float4 hv, float4 wv) {
  return fmaf(hv.x, wv.x,
         fmaf(hv.y, wv.y,
         fmaf(hv.z, wv.z,
         fmaf(hv.w, wv.w, acc))));
}

__device__ __forceinline__ float sigm(float x) { return 1.f / (1.f + expf(-x)); }

// ---------------- fused two-layer step (one launch per phase) ----------------
// Phase t: blocks 0..127   = L1 step t      (16 b x 64 cols, K=512)
//          blocks 128..383 = L2 step t-1    ( 8 b x 64 cols, K=1024: [h1;h2]@W2)
__global__ __launch_bounds__(256, 2)
void fused_step(const float* __restrict__ pre, const float* __restrict__ WT1,
                const float* __restrict__ WT2, const float* __restrict__ b2,
                float* __restrict__ h1ring, float* __restrict__ h2all,
                float* __restrict__ c1, float* __restrict__ c2, int t) {
  __shared__ float hs[8256];       // L1: [16][516]  L2: [8][1032]
  __shared__ float ex[64 * 17];    // [col j][b]
  const int tid = threadIdx.x;
  const int q   = tid >> 4;        // 0..15
  const int ks  = tid & 15;        // 0..15
  const int g   = q >> 2;          // gate 0..3
  const int mq  = (q & 3) * 4;     // col-quad offset within gate's 16 m's

  if (blockIdx.x < 128) {
    if (t >= Tt) return;
    const int bg = blockIdx.x >> 5, cg = blockIdx.x & 31;
    const int b0 = bg * 16, m0 = cg * 16;
    const float* Wbase = WT1 + (size_t)(g * 512 + m0 + mq) * 512;

    float acc[16][4];
#pragma unroll
    for (int b = 0; b < 16; ++b)
#pragma unroll
      for (int c = 0; c < 4; ++c) acc[b][c] = 0.f;

    if (t > 0) {
      const float* hsrc = h1ring + ((size_t)(((t - 1) & 1) * 64 + b0)) * 512;
#pragma unroll
      for (int s = 0; s < 8; ++s) {
        const int v = tid + s * 256;
        const int row = v >> 7, f4 = v & 127;
        *(float4*)(&hs[row * 516 + f4 * 4]) =
            *(const float4*)(hsrc + row * 512 + f4 * 4);
      }
      __syncthreads();
#pragma unroll
      for (int it = 0; it < 8; ++it) {
        const int k = it * 64 + ks * 4;
        const float4 w0 = *(const float4*)(Wbase + k);
        const float4 w1 = *(const float4*)(Wbase + 512 + k);
        const float4 w2 = *(const float4*)(Wbase + 1024 + k);
        const float4 w3 = *(const float4*)(Wbase + 1536 + k);
#pragma unroll
        for (int b = 0; b < 16; ++b) {
          const float4 hv = *(const float4*)(&hs[b * 516 + k]);
          acc[b][0] = dot4(acc[b][0], hv, w0);
          acc[b][1] = dot4(acc[b][1], hv, w1);
          acc[b][2] = dot4(acc[b][2], hv, w2);
          acc[b][3] = dot4(acc[b][3], hv, w3);
        }
      }
    }
#pragma unroll
    for (int b = 0; b < 16; ++b)
#pragma unroll
      for (int c = 0; c < 4; ++c) {
        float v = acc[b][c];
        v += __shfl_xor(v, 1); v += __shfl_xor(v, 2);
        v += __shfl_xor(v, 4); v += __shfl_xor(v, 8);
        acc[b][c] = v;
      }
#pragma unroll
    for (int b = 0; b < 16; ++b)
      if (ks == b) {
#pragma unroll
        for (int c = 0; c < 4; ++c) ex[(q * 4 + c) * 17 + b] = acc[b][c];
      }
    __syncthreads();

    {
      const int b = tid >> 4, ml = tid & 15;
      const size_t prow = ((size_t)(b0 + b) * Tt + t) * Gg + m0 + ml;
      const float gi = pre[prow]        + ex[(0 * 16 + ml) * 17 + b];
      const float gj = pre[prow + 512]  + ex[(1 * 16 + ml) * 17 + b];
      const float gf = pre[prow + 1024] + ex[(2 * 16 + ml) * 17 + b];
      const float go = pre[prow + 1536] + ex[(3 * 16 + ml) * 17 + b];
      const int ci = (b0 + b) * Hh + m0 + ml;
      const float cp = (t > 0) ? c1[ci] : 0.f;
      const float nc = fmaf(cp, sigm(gf + 1.f), sigm(gi) * tanhf(gj));
      c1[ci] = nc;
      h1ring[((size_t)((t & 1) * 64 + b0 + b)) * 512 + m0 + ml] =
          tanhf(nc) * sigm(go);
    }
  } else {
    if (t < 1) return;
    const int idx = blockIdx.x - 128;
    const int bg = idx >> 5, cg = idx & 31;
    const int b0 = bg * 8, m0 = cg * 16;
    const float* Wbase = WT2 + (size_t)(g * 512 + m0 + mq) * 1024;

    float acc[8][4];
#pragma unroll
    for (int b = 0; b < 8; ++b)
#pragma unroll
      for (int c = 0; c < 4; ++c) acc[b][c] = 0.f;

    const float* h1src = h1ring + ((size_t)(((t - 1) & 1) * 64 + b0)) * 512;
#pragma unroll
    for (int s = 0; s < 8; ++s) {
      const int v = tid + s * 256;
      const int row = v >> 8, f4 = v & 255;
      float4 hv;
      if (f4 < 128) {
        hv = *(const float4*)(h1src + row * 512 + f4 * 4);
      } else if (t >= 2) {
        hv = *(const float4*)(h2all +
              ((size_t)(b0 + row) * Tt + (t - 2)) * 512 + (f4 - 128) * 4);
      } else {
        hv = make_float4(0.f, 0.f, 0.f, 0.f);
      }
      *(float4*)(&hs[row * 1032 + f4 * 4]) = hv;
    }
    __syncthreads();
#pragma unroll
    for (int it = 0; it < 16; ++it) {
      const int k = it * 64 + ks * 4;
      const float4 w0 = *(const float4*)(Wbase + k);
      const float4 w1 = *(const float4*)(Wbase + 1024 + k);
      const float4 w2 = *(const float4*)(Wbase + 2048 + k);
      const float4 w3 = *(const float4*)(Wbase + 3072 + k);
#pragma unroll
      for (int b = 0; b < 8; ++b) {
        const float4 hv = *(const float4*)(&hs[b * 1032 + k]);
        acc[b][0] = dot4(acc[b][0], hv, w0);
        acc[b][1] = dot4(acc[b][1], hv, w1);
        acc[b][2] = dot4(acc[b][2], hv, w2);
        acc[b][3] = dot4(acc[b][3], hv, w3);
      }
    }
#pragma unroll
    for (int b = 0; b < 8; ++b)
#pragma unroll
      for (int c = 0; c < 4; ++c) {
        float v = acc[b][c];
        v += __shfl_xor(v, 1); v += __shfl_xor(v, 2);
        v += __shfl_xor(v, 4); v += __shfl_xor(v, 8);
        acc[b][c] = v;
      }
#pragma unroll
    for (int b = 0; b < 8; ++b)
      if (ks == b) {
#pragma unroll
        for (int c = 0; c < 4; ++c) ex[(q * 4 + c) * 17 + b] = acc[b][c];
      }
    __syncthreads();

    if (tid < 128) {
      const int b = tid >> 4, ml = tid & 15;
      const float gi = b2[0 * 512 + m0 + ml] + ex[(0 * 16 + ml) * 17 + b];
      const float gj = b2[1 * 512 + m0 + ml] + ex[(1 * 16 + ml) * 17 + b];
      const float gf = b2[2 * 512 + m0 + ml] + ex[(2 * 16 + ml) * 17 + b];
      const float go = b2[3 * 512 + m0 + ml] + ex[(3 * 16 + ml) * 17 + b];
      const int ci = (b0 + b) * Hh + m0 + ml;
      const float cp = (t >= 2) ? c2[ci] : 0.f;
      const float nc = fmaf(cp, sigm(gf + 1.f), sigm(gi) * tanhf(gj));
      c2[ci] = nc;
      h2all[((size_t)(b0 + b) * Tt + (t - 1)) * 512 + m0 + ml] =
          tanhf(nc) * sigm(go);
    }
  }
}

// ---------------- Output projection + softmax + CE ----------------
__global__ __launch_bounds__(128)
void proj_softmax(const float* __restrict__ h2, const float* __restrict__ Wout,
                  const float* __restrict__ bout, const int* __restrict__ labels,
                  float* __restrict__ preds, float* __restrict__ ce) {
  __shared__ float hs[8][Hh];
  __shared__ float wred[2][2];
  const int tid = threadIdx.x;
  const int wid = tid >> 6;
  const int r0  = blockIdx.x * 8;

  for (int i = tid; i < 8 * (Hh / 4); i += 128) {
    const int row = i >> 7;
    const int c4  = i & 127;
    ((float4*)hs[row])[c4] =
        ((const float4*)(h2 + ((size_t)(r0 + row) * Hh)))[c4];
  }
  __syncthreads();

  const bool act = (tid < Cc);
  float acc[8];
  {
    const float bj = act ? bout[tid] : 0.f;
#pragma unroll
    for (int i = 0; i < 8; ++i) acc[i] = bj;
  }
  if (act) {
#pragma unroll 4
    for (int k = 0; k < Hh; ++k) {
      const float w = Wout[k * Cc + tid];
#pragma unroll
      for (int i = 0; i < 8; ++i) acc[i] = fmaf(hs[i][k], w, acc[i]);
    }
  }

  for (int row = 0; row < 8; ++row) {
    const float v = act ? acc[row] : -INFINITY;
    float mw = v;
#pragma unroll
    for (int off = 32; off > 0; off >>= 1) mw = fmaxf(mw, __shfl_xor(mw, off));
    if ((tid & 63) == 0) wred[0][wid] = mw;
    __syncthreads();
    const float mx = fmaxf(wred[0][0], wred[0][1]);
    const float e = act ? expf(v - mx) : 0.f;
    float sw = e;
#pragma unroll
    for (int off = 32; off > 0; off >>= 1) sw += __shfl_xor(sw, off);
    if ((tid & 63) == 0) wred[1][wid] = sw;
    __syncthreads();
    const float sum = wred[1][0] + wred[1][1];
    if (act) preds[(size_t)(r0 + row) * Cc + tid] = e / sum;
    const int lab = labels[r0 + row];
    if (tid == lab) ce[r0 + row] = logf(sum) + mx - v;
    __syncthreads();
  }
}

__global__ __launch_bounds__(256)
void reduce_cost(const float* __restrict__ ce, float* __restrict__ out) {
  __shared__ float red[256];
  const int tid = threadIdx.x;
  float s = 0.f;
  for (int i = tid; i < ROWS; i += 256) s += ce[i];
  red[tid] = s;
  __syncthreads();
  for (int st = 128; st > 0; st >>= 1) {
    if (tid < st) red[tid] += red[tid + st];
    __syncthreads();
  }
  if (tid == 0) out[0] = red[0] / (float)Bb;
}

// ---------------- launch ----------------
extern "C" void kernel_launch(void* const* d_in, const int* in_sizes, int n_in,
                              void* d_out, int out_size, void* d_ws, size_t ws_size,
                              hipStream_t stream) {
  const float* inputs = (const float*)d_in[0];
  const int*   labels = (const int*)d_in[1];
  const float* W1     = (const float*)d_in[2];
  const float* b1     = (const float*)d_in[3];
  const float* W2     = (const float*)d_in[4];
  const float* b2     = (const float*)d_in[5];
  const float* Wout   = (const float*)d_in[6];
  const float* bout   = (const float*)d_in[7];
  float* out = (float*)d_out;

  float* ws     = (float*)d_ws;
  float* pre    = ws;                              // ROWS*Gg        (64M B)
  float* h2all  = pre    + (size_t)ROWS * Gg;      // ROWS*Hh
  float* h1ring = h2all  + (size_t)ROWS * Hh;      // 2*64*512
  float* c1     = h1ring + 2 * 64 * 512;
  float* c2     = c1     + (size_t)Bb * Hh;
  float* WT1    = c2     + (size_t)Bb * Hh;        // 2048*512
  float* WT2    = WT1    + (size_t)Gg * Hh;        // 2048*1024
  float* ceb    = WT2    + (size_t)Gg * 2 * Hh;    // ROWS
  float* fend   = ceb    + ROWS;
  // bf16 arrays (u16) after the fp32 region
  u16* Xhi  = (u16*)fend;                          // ROWS*Dd
  u16* Xlo  = Xhi  + (size_t)ROWS * Dd;
  u16* W1Th = Xlo  + (size_t)ROWS * Dd;            // Gg*Dd
  u16* W1Tl = W1Th + (size_t)Gg * Dd;
  const size_t need = (size_t)((char*)(W1Tl + (size_t)Gg * Dd) - (char*)d_ws);
  const bool use_mfma = ws_size >= need;

  transposeW<<<dim3(16, 64, 3), dim3(32, 8), 0, stream>>>(W1, W2, WT1, WT2);

  if (use_mfma) {
    convert_hilo<<<2048, 256, 0, stream>>>(inputs, Xhi, Xlo, ROWS * Dd / 4);
    convertT_w1<<<dim3(64, 64), dim3(32, 8), 0, stream>>>(W1, W1Th, W1Tl);
    gemm1_mfma<<<dim3(Gg / 128, ROWS / 128), 256, 0, stream>>>(
        Xhi, Xlo, W1Th, W1Tl, b1, pre);
  } else {
    sgemm_bias<<<dim3(Gg / BN, ROWS / BM), dim3(256), 0, stream>>>(
        inputs, W1, b1, pre, ROWS, Gg, Dd);
  }

  for (int t = 0; t <= Tt; ++t)
    fused_step<<<384, 256, 0, stream>>>(pre, WT1, WT2, b2,
                                        h1ring, h2all, c1, c2, t);

  proj_softmax<<<ROWS / 8, 128, 0, stream>>>(h2all, Wout, bout, labels, out, ceb);
  reduce_cost<<<1, 256, 0, stream>>>(ceb, out + (size_t)ROWS * Cc);
}

// Round 7
// 2058.544 us; speedup vs baseline: 5.7284x; 1.0838x over previous
//
#include <hip/hip_runtime.h>
#include <cmath>

// Problem constants
#define Bb   64
#define Tt   128
#define Dd   2048
#define Hh   512
#define Gg   2048      // 4*H
#define Cc   101
#define ROWS 8192      // B*T

typedef unsigned short u16;
typedef __attribute__((ext_vector_type(8))) short bf16x8;
typedef __attribute__((ext_vector_type(4))) float f32x4;

// ---------------- bf16 hi/lo split helpers ----------------
__device__ __forceinline__ u16 bf16rne(float x) {
  unsigned u = __float_as_uint(x);
  unsigned r = (u + 0x7fffu + ((u >> 16) & 1u)) >> 16;
  return (u16)r;
}
__device__ __forceinline__ void split_bf16(float x, u16& h, u16& l) {
  h = bf16rne(x);
  l = bf16rne(x - __uint_as_float(((unsigned)h) << 16));
}
__device__ __forceinline__ float sigm(float x) { return 1.f / (1.f + expf(-x)); }

// X [ROWS x Dd] fp32 -> Xhi, Xlo bf16 (same layout)
__global__ __launch_bounds__(256)
void convert_hilo(const float* __restrict__ src, u16* __restrict__ hi,
                  u16* __restrict__ lo, int n4) {
  for (int i = blockIdx.x * 256 + threadIdx.x; i < n4; i += gridDim.x * 256) {
    const float4 v = ((const float4*)src)[i];
    ushort4 h, l;
    split_bf16(v.x, h.x, l.x);
    split_bf16(v.y, h.y, l.y);
    split_bf16(v.z, h.z, l.z);
    split_bf16(v.w, h.w, l.w);
    ((ushort4*)hi)[i] = h;
    ((ushort4*)lo)[i] = l;
  }
}

// W1 top [Dd x Gg] -> W1T hi/lo [Gg x Dd] bf16  (for gemm1 B operand)
__global__ __launch_bounds__(256)
void convertT_w1(const float* __restrict__ W1, u16* __restrict__ Th,
                 u16* __restrict__ Tl) {
  __shared__ float tl[32][33];
  const int tx = threadIdx.x, ty = threadIdx.y;   // 32, 8
  const int k0 = blockIdx.x * 32, c0 = blockIdx.y * 32;
#pragma unroll
  for (int j = 0; j < 4; ++j)
    tl[ty + j * 8][tx] = W1[(size_t)(k0 + ty + j * 8) * Gg + (c0 + tx)];
  __syncthreads();
#pragma unroll
  for (int j = 0; j < 4; ++j) {
    const float v = tl[tx][ty + j * 8];
    u16 h, l;
    split_bf16(v, h, l);
    const size_t o = (size_t)(c0 + ty + j * 8) * Dd + (k0 + tx);
    Th[o] = h;
    Tl[o] = l;
  }
}

// Recurrent weights, permuted + split:
// WP[cg 128][vc 16][K], vc = g*4 + m for col = g*512 + cg*4 + m.
// src = W [K x 2048] row-major (WP1: W1 rows Dd.. ; WP2: W2 rows 0..1023).
__global__ __launch_bounds__(256)
void permuteW(const float* __restrict__ src, u16* __restrict__ dh,
              u16* __restrict__ dl, int K) {
  __shared__ float tl[32][33];
  const int tx = threadIdx.x, ty = threadIdx.y;   // 32, 8
  const int k0 = blockIdx.x * 32, c0 = blockIdx.y * 32;
#pragma unroll
  for (int j = 0; j < 4; ++j)
    tl[ty + j * 8][tx] = src[(size_t)(k0 + ty + j * 8) * Gg + (c0 + tx)];
  __syncthreads();
#pragma unroll
  for (int j = 0; j < 4; ++j) {
    const int col = c0 + ty + j * 8;
    const int g = col >> 9, mg = col & 511;
    const int cg = mg >> 2, m = mg & 3;
    const float v = tl[tx][ty + j * 8];
    u16 h, l;
    split_bf16(v, h, l);
    const size_t o = (size_t)(cg * 16 + g * 4 + m) * K + k0 + tx;
    dh[o] = h;
    dl[o] = l;
  }
}

// ---------------- MFMA bf16x3 GEMM: pre = X @ W1 + b1 ----------------
__global__ __launch_bounds__(256)
void gemm1_mfma(const u16* __restrict__ Ah, const u16* __restrict__ Al,
                const u16* __restrict__ Bh, const u16* __restrict__ Bl,
                const float* __restrict__ bias, float* __restrict__ C) {
  __shared__ u16 Ash[128][40];
  __shared__ u16 Asl[128][40];
  __shared__ u16 Bsh[128][40];
  __shared__ u16 Bsl[128][40];
  const int tid  = threadIdx.x;
  const int lane = tid & 63, wave = tid >> 6;
  const int wm = wave >> 1, wn = wave & 1;
  const int l15 = lane & 15, k8 = (lane >> 4) * 8, r4 = (lane >> 4) * 4;
  const int row0 = blockIdx.y * 128, col0 = blockIdx.x * 128;
  const int srow = tid >> 1, sk = (tid & 1) * 16;

  const u16* pAh = Ah + (size_t)(row0 + srow) * Dd + sk;
  const u16* pAl = Al + (size_t)(row0 + srow) * Dd + sk;
  const u16* pBh = Bh + (size_t)(col0 + srow) * Dd + sk;
  const u16* pBl = Bl + (size_t)(col0 + srow) * Dd + sk;

  f32x4 acc[4][4];
#pragma unroll
  for (int i = 0; i < 4; ++i)
#pragma unroll
    for (int j = 0; j < 4; ++j) acc[i][j] = (f32x4){0.f, 0.f, 0.f, 0.f};

  for (int k0 = 0; k0 < Dd; k0 += 32) {
    *(bf16x8*)(&Ash[srow][sk])     = *(const bf16x8*)(pAh + k0);
    *(bf16x8*)(&Ash[srow][sk + 8]) = *(const bf16x8*)(pAh + k0 + 8);
    *(bf16x8*)(&Asl[srow][sk])     = *(const bf16x8*)(pAl + k0);
    *(bf16x8*)(&Asl[srow][sk + 8]) = *(const bf16x8*)(pAl + k0 + 8);
    *(bf16x8*)(&Bsh[srow][sk])     = *(const bf16x8*)(pBh + k0);
    *(bf16x8*)(&Bsh[srow][sk + 8]) = *(const bf16x8*)(pBh + k0 + 8);
    *(bf16x8*)(&Bsl[srow][sk])     = *(const bf16x8*)(pBl + k0);
    *(bf16x8*)(&Bsl[srow][sk + 8]) = *(const bf16x8*)(pBl + k0 + 8);
    __syncthreads();

    bf16x8 afh[4], afl[4], bfh[4], bfl[4];
#pragma unroll
    for (int mt = 0; mt < 4; ++mt) {
      afh[mt] = *(const bf16x8*)(&Ash[wm * 64 + mt * 16 + l15][k8]);
      afl[mt] = *(const bf16x8*)(&Asl[wm * 64 + mt * 16 + l15][k8]);
    }
#pragma unroll
    for (int nt = 0; nt < 4; ++nt) {
      bfh[nt] = *(const bf16x8*)(&Bsh[wn * 64 + nt * 16 + l15][k8]);
      bfl[nt] = *(const bf16x8*)(&Bsl[wn * 64 + nt * 16 + l15][k8]);
    }
#pragma unroll
    for (int mt = 0; mt < 4; ++mt)
#pragma unroll
      for (int nt = 0; nt < 4; ++nt) {
        acc[mt][nt] = __builtin_amdgcn_mfma_f32_16x16x32_bf16(
            afh[mt], bfh[nt], acc[mt][nt], 0, 0, 0);
        acc[mt][nt] = __builtin_amdgcn_mfma_f32_16x16x32_bf16(
            afh[mt], bfl[nt], acc[mt][nt], 0, 0, 0);
        acc[mt][nt] = __builtin_amdgcn_mfma_f32_16x16x32_bf16(
            afl[mt], bfh[nt], acc[mt][nt], 0, 0, 0);
      }
    __syncthreads();
  }

#pragma unroll
  for (int nt = 0; nt < 4; ++nt) {
    const int col = col0 + wn * 64 + nt * 16 + l15;
    const float bj = bias[col];
#pragma unroll
    for (int mt = 0; mt < 4; ++mt) {
      float* Cp = C + (size_t)(row0 + wm * 64 + mt * 16 + r4) * Gg + col;
#pragma unroll
      for (int r = 0; r < 4; ++r)
        Cp[(size_t)r * Gg] = acc[mt][nt][r] + bj;
    }
  }
}

// ---------------- SGEMM (fp32 fallback if ws too small) ----------------
#define BM 128
#define BN 128
#define BK 16

__global__ __launch_bounds__(256)
void sgemm_bias(const float* __restrict__ A, const float* __restrict__ B,
                const float* __restrict__ bias, float* __restrict__ C,
                int M, int N, int K) {
  __shared__ float As[BK][BM];
  __shared__ float Bs[BK][BN];
  const int tid  = threadIdx.x;
  const int row0 = blockIdx.y * BM, col0 = blockIdx.x * BN;
  const int tr = (tid >> 4) << 3;
  const int tc = (tid & 15) << 3;

  float acc[8][8];
#pragma unroll
  for (int i = 0; i < 8; ++i)
#pragma unroll
    for (int j = 0; j < 8; ++j) acc[i][j] = 0.f;

  const int arow = tid >> 1;
  const int acol = (tid & 1) << 3;
  const int brow = tid >> 4;
  const int bcol = (tid & 15) << 3;
  const float* Ap = A + (size_t)(row0 + arow) * K + acol;
  const float* Bp = B + (size_t)brow * N + (col0 + bcol);

  for (int k0 = 0; k0 < K; k0 += BK) {
    const float4 a0 = *(const float4*)(Ap + k0);
    const float4 a1 = *(const float4*)(Ap + k0 + 4);
    const float4 bv0 = *(const float4*)(Bp + (size_t)k0 * N);
    const float4 bv1 = *(const float4*)(Bp + (size_t)k0 * N + 4);
    As[acol + 0][arow] = a0.x;
    As[acol + 1][arow] = a0.y;
    As[acol + 2][arow] = a0.z;
    As[acol + 3][arow] = a0.w;
    As[acol + 4][arow] = a1.x;
    As[acol + 5][arow] = a1.y;
    As[acol + 6][arow] = a1.z;
    As[acol + 7][arow] = a1.w;
    *(float4*)(&Bs[brow][bcol])     = bv0;
    *(float4*)(&Bs[brow][bcol + 4]) = bv1;
    __syncthreads();
#pragma unroll
    for (int k = 0; k < BK; ++k) {
      float a[8], b[8];
      *(float4*)(a)     = *(const float4*)(&As[k][tr]);
      *(float4*)(a + 4) = *(const float4*)(&As[k][tr + 4]);
      *(float4*)(b)     = *(const float4*)(&Bs[k][tc]);
      *(float4*)(b + 4) = *(const float4*)(&Bs[k][tc + 4]);
#pragma unroll
      for (int i = 0; i < 8; ++i)
#pragma unroll
        for (int j = 0; j < 8; ++j)
          acc[i][j] = fmaf(a[i], b[j], acc[i][j]);
    }
    __syncthreads();
  }

  float bj[8];
#pragma unroll
  for (int j = 0; j < 8; ++j) bj[j] = bias[col0 + tc + j];
#pragma unroll
  for (int i = 0; i < 8; ++i) {
    float* Cp = C + (size_t)(row0 + tr + i) * N + (col0 + tc);
    float4 o0, o1;
    o0.x = acc[i][0] + bj[0]; o0.y = acc[i][1] + bj[1];
    o0.z = acc[i][2] + bj[2]; o0.w = acc[i][3] + bj[3];
    o1.x = acc[i][4] + bj[4]; o1.y = acc[i][5] + bj[5];
    o1.z = acc[i][6] + bj[6]; o1.w = acc[i][7] + bj[7];
    *(float4*)(Cp)     = o0;
    *(float4*)(Cp + 4) = o1;
  }
}

// ---------------- MFMA fused step ----------------
// One launch per phase t: blocks 0..127 = L1 step t (cg = blockIdx),
// 128..255 = L2 step t-1 (K=1024 = [h1[t-1]; h2[t-2]]).
// Block: all 64 batches x 16 strided cols {g*512 + cg*4 + m}.
// wave w = batch tile (16 rows); bf16x3 MFMA; A/B double-buffered per 32-k chunk.
__device__ __forceinline__ void mm_half(
    const u16* __restrict__ hh_src, const u16* __restrict__ hl_src,
    const u16* __restrict__ wph, const u16* __restrict__ wpl, int Kw,
    f32x4& acc, u16 (*Ah)[64][40], u16 (*Al)[64][40],
    u16 (*Bh)[16][40], u16 (*Bl)[16][40], int tid, int lane, int w) {
  const int hr = tid >> 2, hk = (tid & 3) * 8;
  const int wv = tid >> 4, wk = (tid & 15) * 2;
  const int fr = lane & 15, f8 = (lane >> 4) * 8;

  bf16x8 rah = *(const bf16x8*)(hh_src + hr * 512 + hk);
  bf16x8 ral = *(const bf16x8*)(hl_src + hr * 512 + hk);
  unsigned rwh = *(const unsigned*)(wph + (size_t)wv * Kw + wk);
  unsigned rwl = *(const unsigned*)(wpl + (size_t)wv * Kw + wk);
  *(bf16x8*)&Ah[0][hr][hk] = rah;
  *(bf16x8*)&Al[0][hr][hk] = ral;
  *(unsigned*)&Bh[0][wv][wk] = rwh;
  *(unsigned*)&Bl[0][wv][wk] = rwl;
  __syncthreads();

  for (int kc = 0; kc < 16; ++kc) {
    const int cur = kc & 1;
    if (kc < 15) {
      rah = *(const bf16x8*)(hh_src + hr * 512 + (kc + 1) * 32 + hk);
      ral = *(const bf16x8*)(hl_src + hr * 512 + (kc + 1) * 32 + hk);
      rwh = *(const unsigned*)(wph + (size_t)wv * Kw + (kc + 1) * 32 + wk);
      rwl = *(const unsigned*)(wpl + (size_t)wv * Kw + (kc + 1) * 32 + wk);
    }
    const bf16x8 afh = *(const bf16x8*)&Ah[cur][w * 16 + fr][f8];
    const bf16x8 afl = *(const bf16x8*)&Al[cur][w * 16 + fr][f8];
    const bf16x8 bfh = *(const bf16x8*)&Bh[cur][fr][f8];
    const bf16x8 bfl = *(const bf16x8*)&Bl[cur][fr][f8];
    acc = __builtin_amdgcn_mfma_f32_16x16x32_bf16(afh, bfh, acc, 0, 0, 0);
    acc = __builtin_amdgcn_mfma_f32_16x16x32_bf16(afh, bfl, acc, 0, 0, 0);
    acc = __builtin_amdgcn_mfma_f32_16x16x32_bf16(afl, bfh, acc, 0, 0, 0);
    if (kc < 15) {
      *(bf16x8*)&Ah[cur ^ 1][hr][hk] = rah;
      *(bf16x8*)&Al[cur ^ 1][hr][hk] = ral;
      *(unsigned*)&Bh[cur ^ 1][wv][wk] = rwh;
      *(unsigned*)&Bl[cur ^ 1][wv][wk] = rwl;
    }
    __syncthreads();
  }
}

__global__ __launch_bounds__(256, 1)
void fused_step2(const float* __restrict__ pre,
                 const u16* __restrict__ WP1h, const u16* __restrict__ WP1l,
                 const u16* __restrict__ WP2h, const u16* __restrict__ WP2l,
                 const float* __restrict__ b2,
                 u16* __restrict__ h1hi, u16* __restrict__ h1lo,
                 u16* __restrict__ h2hi, u16* __restrict__ h2lo,
                 float* __restrict__ h2all,
                 float* __restrict__ c1, float* __restrict__ c2, int t) {
  __shared__ u16 Ah[2][64][40], Al[2][64][40];
  __shared__ u16 Bh[2][16][40], Bl[2][16][40];
  __shared__ float ex[4][16][16];
  const int tid = threadIdx.x;
  const int lane = tid & 63, w = tid >> 6;
  const int fr = lane & 15;
  const bool isL2 = blockIdx.x >= 128;
  const int cg = blockIdx.x & 127;

  f32x4 acc = {0.f, 0.f, 0.f, 0.f};
  bool have = false;

  if (!isL2) {
    if (t >= Tt) return;
    if (t > 0) {
      const int sl = (t - 1) & 1;
      mm_half(h1hi + (sl << 15), h1lo + (sl << 15),
              WP1h + (size_t)cg * 16 * 512, WP1l + (size_t)cg * 16 * 512, 512,
              acc, Ah, Al, Bh, Bl, tid, lane, w);
      have = true;
    }
  } else {
    if (t < 1) return;
    const u16* ph = WP2h + (size_t)cg * 16 * 1024;
    const u16* pl = WP2l + (size_t)cg * 16 * 1024;
    {
      const int sl = (t - 1) & 1;
      mm_half(h1hi + (sl << 15), h1lo + (sl << 15), ph, pl, 1024,
              acc, Ah, Al, Bh, Bl, tid, lane, w);
    }
    if (t >= 2) {
      const int sl = (t - 2) & 1;
      mm_half(h2hi + (sl << 15), h2lo + (sl << 15), ph + 512, pl + 512, 1024,
              acc, Ah, Al, Bh, Bl, tid, lane, w);
    }
    have = true;
  }

  if (have) {
#pragma unroll
    for (int r = 0; r < 4; ++r)
      ex[w][(lane >> 4) * 4 + r][fr] = acc[r];
  }
  __syncthreads();

  // epilogue: thread -> (batch b, local m); col = cg*4 + m
  const int b = tid >> 2, m = tid & 3;
  float s0 = 0.f, s1 = 0.f, s2 = 0.f, s3 = 0.f;
  if (have) {
    s0 = ex[b >> 4][b & 15][0 + m];
    s1 = ex[b >> 4][b & 15][4 + m];
    s2 = ex[b >> 4][b & 15][8 + m];
    s3 = ex[b >> 4][b & 15][12 + m];
  }
  const int col = cg * 4 + m;
  const int ci = b * Hh + col;
  if (!isL2) {
    const float* pp = pre + ((size_t)b * Tt + t) * Gg + col;
    const float gi = pp[0] + s0, gj = pp[512] + s1;
    const float gf = pp[1024] + s2, go = pp[1536] + s3;
    const float cp = (t > 0) ? c1[ci] : 0.f;
    const float nc = fmaf(cp, sigm(gf + 1.f), sigm(gi) * tanhf(gj));
    c1[ci] = nc;
    const float nh = tanhf(nc) * sigm(go);
    u16 hh, hl;
    split_bf16(nh, hh, hl);
    const int hidx = ((t & 1) << 15) + ci;
    h1hi[hidx] = hh;
    h1lo[hidx] = hl;
  } else {
    const float gi = b2[col] + s0, gj = b2[512 + col] + s1;
    const float gf = b2[1024 + col] + s2, go = b2[1536 + col] + s3;
    const float cp = (t >= 2) ? c2[ci] : 0.f;
    const float nc = fmaf(cp, sigm(gf + 1.f), sigm(gi) * tanhf(gj));
    c2[ci] = nc;
    const float nh = tanhf(nc) * sigm(go);
    h2all[((size_t)b * Tt + (t - 1)) * Hh + col] = nh;
    u16 hh, hl;
    split_bf16(nh, hh, hl);
    const int hidx = (((t - 1) & 1) << 15) + ci;
    h2hi[hidx] = hh;
    h2lo[hidx] = hl;
  }
}

// ---------------- Output projection + softmax + CE ----------------
__global__ __launch_bounds__(128)
void proj_softmax(const float* __restrict__ h2, const float* __restrict__ Wout,
                  const float* __restrict__ bout, const int* __restrict__ labels,
                  float* __restrict__ preds, float* __restrict__ ce) {
  __shared__ float hs[8][Hh];
  __shared__ float wred[2][2];
  const int tid = threadIdx.x;
  const int wid = tid >> 6;
  const int r0  = blockIdx.x * 8;

  for (int i = tid; i < 8 * (Hh / 4); i += 128) {
    const int row = i >> 7;
    const int c4  = i & 127;
    ((float4*)hs[row])[c4] =
        ((const float4*)(h2 + ((size_t)(r0 + row) * Hh)))[c4];
  }
  __syncthreads();

  const bool act = (tid < Cc);
  float acc[8];
  {
    const float bj = act ? bout[tid] : 0.f;
#pragma unroll
    for (int i = 0; i < 8; ++i) acc[i] = bj;
  }
  if (act) {
#pragma unroll 4
    for (int k = 0; k < Hh; ++k) {
      const float w = Wout[k * Cc + tid];
#pragma unroll
      for (int i = 0; i < 8; ++i) acc[i] = fmaf(hs[i][k], w, acc[i]);
    }
  }

  for (int row = 0; row < 8; ++row) {
    const float v = act ? acc[row] : -INFINITY;
    float mw = v;
#pragma unroll
    for (int off = 32; off > 0; off >>= 1) mw = fmaxf(mw, __shfl_xor(mw, off));
    if ((tid & 63) == 0) wred[0][wid] = mw;
    __syncthreads();
    const float mx = fmaxf(wred[0][0], wred[0][1]);
    const float e = act ? expf(v - mx) : 0.f;
    float sw = e;
#pragma unroll
    for (int off = 32; off > 0; off >>= 1) sw += __shfl_xor(sw, off);
    if ((tid & 63) == 0) wred[1][wid] = sw;
    __syncthreads();
    const float sum = wred[1][0] + wred[1][1];
    if (act) preds[(size_t)(r0 + row) * Cc + tid] = e / sum;
    const int lab = labels[r0 + row];
    if (tid == lab) ce[r0 + row] = logf(sum) + mx - v;
    __syncthreads();
  }
}

__global__ __launch_bounds__(256)
void reduce_cost(const float* __restrict__ ce, float* __restrict__ out) {
  __shared__ float red[256];
  const int tid = threadIdx.x;
  float s = 0.f;
  for (int i = tid; i < ROWS; i += 256) s += ce[i];
  red[tid] = s;
  __syncthreads();
  for (int st = 128; st > 0; st >>= 1) {
    if (tid < st) red[tid] += red[tid + st];
    __syncthreads();
  }
  if (tid == 0) out[0] = red[0] / (float)Bb;
}

// ---------------- launch ----------------
extern "C" void kernel_launch(void* const* d_in, const int* in_sizes, int n_in,
                              void* d_out, int out_size, void* d_ws, size_t ws_size,
                              hipStream_t stream) {
  const float* inputs = (const float*)d_in[0];
  const int*   labels = (const int*)d_in[1];
  const float* W1     = (const float*)d_in[2];
  const float* b1     = (const float*)d_in[3];
  const float* W2     = (const float*)d_in[4];
  const float* b2     = (const float*)d_in[5];
  const float* Wout   = (const float*)d_in[6];
  const float* bout   = (const float*)d_in[7];
  float* out = (float*)d_out;

  float* ws    = (float*)d_ws;
  float* pre   = ws;                               // ROWS*Gg   (16M f32)
  float* h2all = pre   + (size_t)ROWS * Gg;        // ROWS*Hh   (4M)
  float* c1    = h2all + (size_t)ROWS * Hh;        // 64*512
  float* c2    = c1    + (size_t)Bb * Hh;
  float* ceb   = c2    + (size_t)Bb * Hh;          // ROWS
  u16* h1hi = (u16*)(ceb + ROWS);                  // [2][64][512]
  u16* h1lo = h1hi + 2 * 64 * 512;
  u16* h2hi = h1lo + 2 * 64 * 512;
  u16* h2lo = h2hi + 2 * 64 * 512;
  u16* WP1h = h2lo + 2 * 64 * 512;                 // 128*16*512
  u16* WP1l = WP1h + 128 * 16 * 512;
  u16* WP2h = WP1l + 128 * 16 * 512;               // 128*16*1024
  u16* WP2l = WP2h + 128 * 16 * 1024;
  u16* Xhi  = WP2l + 128 * 16 * 1024;              // ROWS*Dd
  u16* Xlo  = Xhi  + (size_t)ROWS * Dd;
  u16* W1Th = Xlo  + (size_t)ROWS * Dd;            // Gg*Dd
  u16* W1Tl = W1Th + (size_t)Gg * Dd;
  const size_t need = (size_t)((char*)(W1Tl + (size_t)Gg * Dd) - (char*)d_ws);
  const bool use_mfma = ws_size >= need;

  // recurrent weights: permute+split once
  permuteW<<<dim3(16, 64), dim3(32, 8), 0, stream>>>(
      W1 + (size_t)Dd * Gg, WP1h, WP1l, 512);
  permuteW<<<dim3(32, 64), dim3(32, 8), 0, stream>>>(W2, WP2h, WP2l, 1024);

  // Layer 1 input projection: pre = X @ W1[0:D,:] + b1
  if (use_mfma) {
    convert_hilo<<<2048, 256, 0, stream>>>(inputs, Xhi, Xlo, ROWS * Dd / 4);
    convertT_w1<<<dim3(64, 64), dim3(32, 8), 0, stream>>>(W1, W1Th, W1Tl);
    gemm1_mfma<<<dim3(Gg / 128, ROWS / 128), 256, 0, stream>>>(
        Xhi, Xlo, W1Th, W1Tl, b1, pre);
  } else {
    sgemm_bias<<<dim3(Gg / BN, ROWS / BM), dim3(256), 0, stream>>>(
        inputs, W1, b1, pre, ROWS, Gg, Dd);
  }

  // Recurrence: phase t = L1 step t (blocks 0..127) + L2 step t-1 (128..255)
  for (int t = 0; t <= Tt; ++t)
    fused_step2<<<256, 256, 0, stream>>>(pre, WP1h, WP1l, WP2h, WP2l, b2,
                                         h1hi, h1lo, h2hi, h2lo,
                                         h2all, c1, c2, t);

  proj_softmax<<<ROWS / 8, 128, 0, stream>>>(h2all, Wout, bout, labels, out, ceb);
  reduce_cost<<<1, 256, 0, stream>>>(ceb, out + (size_t)ROWS * Cc);
}